// Round 5
// baseline (194.538 us; speedup 1.0000x reference)
//
#include <hip/hip_runtime.h>
#include <math.h>

// FlashAttention fwd, faithful to reference blockwise recurrence INCLUDING the
// e_ij = exp(m_ij - m_new) per-128-block bug. (b,h,s,d)=(2,16,2048,128) fp32.
//
// R5: 32x32x16 f16 MFMA (halves LDS bytes per FLOP vs 16x16x32 — R4 was
// LDS-read-bound at 43.5us/83us). 4 waves/block, each owns 32 q-rows, all
// 128 keys. Swapped QK^T (mfma(K,Q)): D col=lane&31=q -> lane holds one
// q-row's 64 S-values; softmax in registers (63 ops + shfl_xor(32)).
// PV A-frag packed in-register: 4x pack + 2x v_permlane32_swap_b32 per
// k-step (T12). Single-buffered K/V LDS (66 KB) -> 2 blocks/CU; anti-phased
// blocks hide each other's stage-drain (m114). Plain V^T pre-pass (the
// 16x16 slot permutation is no longer needed).

using f16    = _Float16;
using f16x8  = __attribute__((ext_vector_type(8))) _Float16;
using f32x16 = __attribute__((ext_vector_type(16))) float;
typedef unsigned int uint32;

#define SEQ 2048
#define DK  128
#define FA_SCALE 0.08838834764831843f   // 1/sqrt(128)

// ---- pre-pass: Kh = f16(K) [bh][s][d]; Vt = f16(V^T) [bh][d][s] (plain) ----
__global__ __launch_bounds__(256) void prep_kv(const float* __restrict__ K,
                                               const float* __restrict__ V,
                                               f16* __restrict__ Kh,
                                               f16* __restrict__ Vt) {
  __shared__ float Vsh[128][132];          // +4 pad (float4-aligned rows)
  const int st = blockIdx.x, bh = blockIdx.y, tid = threadIdx.x;
  const size_t blk = ((size_t)bh * SEQ + st * 128) * DK;

  // K convert: fully coalesced
  const float* Ksrc = K + blk;
  f16* Kdst = Kh + blk;
#pragma unroll
  for (int i = 0; i < 8; ++i) {
    int u = tid + i * 256;
    float4 a = *(const float4*)(Ksrc + u * 8);
    float4 b = *(const float4*)(Ksrc + u * 8 + 4);
    f16x8 h;
    h[0] = (f16)a.x; h[1] = (f16)a.y; h[2] = (f16)a.z; h[3] = (f16)a.w;
    h[4] = (f16)b.x; h[5] = (f16)b.y; h[6] = (f16)b.z; h[7] = (f16)b.w;
    *(f16x8*)(Kdst + u * 8) = h;
  }

  // V stage (coalesced float4 reads)
  const float* Vsrc = V + blk;
#pragma unroll
  for (int i = 0; i < 16; ++i) {
    int f = tid + i * 256;
    int k = f >> 5, c = f & 31;
    *(float4*)&Vsh[k][c * 4] = *(const float4*)(Vsrc + k * DK + c * 4);
  }
  __syncthreads();

  // gather columns + coalesced stores (4 d-rows x 256B contiguous per instr)
  const int l = tid & 63, wv = tid >> 6;
  const int r = l & 15, dr = l >> 4;
  f16* Vdst = Vt + (size_t)bh * DK * SEQ + st * 128;
#pragma unroll
  for (int it = 0; it < 8; ++it) {
    int d = wv * 32 + it * 4 + dr;
    f16x8 h;
#pragma unroll
    for (int o = 0; o < 8; ++o) h[o] = (f16)Vsh[r * 8 + o][d];
    *(f16x8*)(Vdst + (size_t)d * SEQ + r * 8) = h;
  }
}

// ---------------- main kernel helpers ----------------
__device__ __forceinline__ void gl_lds16(const void* g, void* l) {
  __builtin_amdgcn_global_load_lds(
      (const __attribute__((address_space(1))) unsigned int*)g,
      (__attribute__((address_space(3))) unsigned int*)l, 16, 0, 0);
}

// Stage one 128-row x 256B tile (32 KB) with 4 waves; global source
// pre-swizzled so swizzled reads (byte ^ ((row&7)<<4)) see logical layout.
__device__ __forceinline__ void stage_tile(const char* gbase, size_t gstride,
                                           char* lds, int w, int lg, int ll) {
#pragma unroll
  for (int i = 0; i < 8; ++i) {
    int t = w * 8 + i;                 // 32 x 1KB chunks, 8 per wave
    int row = t * 4 + lg;
    int blog = (ll * 16) ^ ((row & 7) << 4);
    gl_lds16(gbase + (size_t)row * gstride + blog, lds + t * 1024);
  }
}

__device__ __forceinline__ uint32 pkh(float x, float y) {
  union { f16 h[2]; uint32 u; } t;
  t.h[0] = (f16)x; t.h[1] = (f16)y;   // h[0] = low 16 bits = even element
  return t.u;
}

__global__ __launch_bounds__(256, 2) void fa_fwd_f16(
    const float* __restrict__ Q, const f16* __restrict__ Kh,
    const f16* __restrict__ Vt, float* __restrict__ O) {
  // XCD-grouped dispatch, longest-qt-first (LPT makespan)
  const int n = blockIdx.x;
  const int m = n >> 3;
  const int bh = (n & 7) * 4 + (m & 3);
  const int qt = 15 - (m >> 2);

  const int tid  = threadIdx.x;
  const int lane = tid & 63;
  const int w  = tid >> 6;     // wave 0..3: owns q-rows w*32..+31
  const int li = lane & 31;
  const int hi = lane >> 5;
  const int lg = lane >> 4;    // staging only
  const int ll = lane & 15;    // staging only
  const int rsw = (li & 7) << 4;

  __shared__ __align__(16) f16 Ks[128 * 128];   // 32 KB, single-buffered
  __shared__ __align__(16) f16 Vs[128 * 128];   // 32 KB (plain V^T block)
  __shared__ float bc[4][32];                   // per-wave ei/l broadcast
  // 66 KB -> 2 blocks/CU (8 waves/CU = 2/SIMD, anti-phased blocks)

  const float* QB = Q + (size_t)bh * SEQ * DK;
  const char*  KB = (const char*)(Kh + (size_t)bh * SEQ * DK);
  const char*  VB = (const char*)(Vt + (size_t)bh * DK * SEQ);
  float*       OB = O + (size_t)bh * SEQ * DK;

  const int qrow = qt * 128 + w * 32 + li;   // this lane's q-row

  // Q B-frags (FA_SCALE folded): qf[ds] = Q[qrow][ds*16 + hi*8 + 0..7]
  f16x8 qf[8];
#pragma unroll
  for (int ds = 0; ds < 8; ++ds) {
    const float* p = QB + (size_t)qrow * DK + ds * 16 + hi * 8;
    float4 a = *(const float4*)p, b = *(const float4*)(p + 4);
    f16x8 h;
    h[0] = (f16)(a.x * FA_SCALE); h[1] = (f16)(a.y * FA_SCALE);
    h[2] = (f16)(a.z * FA_SCALE); h[3] = (f16)(a.w * FA_SCALE);
    h[4] = (f16)(b.x * FA_SCALE); h[5] = (f16)(b.y * FA_SCALE);
    h[6] = (f16)(b.z * FA_SCALE); h[7] = (f16)(b.w * FA_SCALE);
    qf[ds] = h;
  }

  // U accumulators: u[dt], D-layout row q' = (r&3)+8*(r>>2)+4*hi, col = dt*32+li
  f32x16 u[4];
#pragma unroll
  for (int dt = 0; dt < 4; ++dt) u[dt] = 0;
  float m_run = -INFINITY, lsum = 0.f;

  stage_tile(KB, 256, (char*)Ks, w, lg, ll);
  stage_tile(VB, 4096, (char*)Vs, w, lg, ll);
  __syncthreads();

  for (int kb = 0; kb <= qt; ++kb) {
    // ---- S^T = K Q^T: s[kt] rows k' = (r&3)+8*(r>>2)+4*hi, col q = li ----
    f32x16 s[4];
#pragma unroll
    for (int kt = 0; kt < 4; ++kt) s[kt] = 0;
    __builtin_amdgcn_s_setprio(1);
#pragma unroll
    for (int ds = 0; ds < 8; ++ds) {
      const int boff = (ds * 32 + hi * 16) ^ rsw;
#pragma unroll
      for (int kt = 0; kt < 4; ++kt) {
        f16x8 kf = *(const f16x8*)((const char*)Ks + (kt * 32 + li) * 256 + boff);
        s[kt] = __builtin_amdgcn_mfma_f32_32x32x16_f16(kf, qf[ds], s[kt], 0, 0, 0);
      }
    }
    __builtin_amdgcn_s_setprio(0);

    // ---- causal mask (diag block only) + in-register row max ----
    float mx = -INFINITY;
    if (kb == qt) {
      const int kb0 = kb * 128;
#pragma unroll
      for (int kt = 0; kt < 4; ++kt)
#pragma unroll
        for (int r = 0; r < 16; ++r) {
          const int kg = kb0 + kt * 32 + (r & 3) + 8 * (r >> 2) + 4 * hi;
          float v = s[kt][r];
          if (kg > qrow) v = -INFINITY;
          s[kt][r] = v;
          mx = fmaxf(mx, v);
        }
    } else {
#pragma unroll
      for (int kt = 0; kt < 4; ++kt)
#pragma unroll
        for (int r = 0; r < 16; ++r) mx = fmaxf(mx, s[kt][r]);
    }
    mx = fmaxf(mx, __shfl_xor(mx, 32));   // partner half holds the other 64 k

    const float mn = fmaxf(m_run, mx);    // m_new
    const float ei = __expf(m_run - mn);  // exp(-inf)=0 on first block
    const float ej = __expf(mx - mn);     // the reference's e_ij bug factor
    m_run = mn;

    // ---- P = exp(S - m_new); plain row sum for l ----
    float ps = 0.f;
#pragma unroll
    for (int kt = 0; kt < 4; ++kt)
#pragma unroll
      for (int r = 0; r < 16; ++r) {
        float p = __expf(s[kt][r] - mn);
        s[kt][r] = p;
        ps += p;
      }
    ps += __shfl_xor(ps, 32);
    lsum = ei * lsum + ps;

    // ---- U <- e_i * U: broadcast ei to this lane's 16 U-row owners ----
    bc[w][li] = ei;                       // dup write across hi: same value
    float eu[16];
#pragma unroll
    for (int r = 0; r < 16; ++r)
      eu[r] = bc[w][(r & 3) + 8 * (r >> 2) + 4 * hi];
#pragma unroll
    for (int dt = 0; dt < 4; ++dt)
#pragma unroll
      for (int r = 0; r < 16; ++r) u[dt][r] *= eu[r];

    // ---- U += (e_ij P) V ----
    // A-frag per k-step ks (contract k = ks*16 + (lane>>5)*8 + 0..7):
    //   lane holds k' = (r&3)+8*(r>>2)+4*hi of tile kt=ks>>1, base b0=8*(ks&1)
    //   A=pk(p[b0],p[b0+1]) B=pk(p[b0+2],p[b0+3]) C=pk(p[b0+4],p[b0+5])
    //   D=pk(p[b0+6],p[b0+7]); permlane32_swap(A,C),(B,D) -> frag [A,B,C,D].
    //   Verify lane0 (hi=0): A=(k0,k1) B=(k2,k3); post-swap w2=A(lane32)=(k4,k5),
    //   w3=B(lane32)=(k6,k7) -> elems 0..7 = k0..k7 OK. lane32: w0=C(lane0)=
    //   (k8,k9), w1=D(lane0)=(k10,k11), w2=C(lane32)=(k12,k13), w3=(k14,k15) OK.
    __builtin_amdgcn_s_setprio(1);
#pragma unroll
    for (int ks = 0; ks < 8; ++ks) {
      const int kt = ks >> 1, b0 = (ks & 1) * 8;
      uint32 A = pkh(s[kt][b0 + 0] * ej, s[kt][b0 + 1] * ej);
      uint32 B = pkh(s[kt][b0 + 2] * ej, s[kt][b0 + 3] * ej);
      uint32 C = pkh(s[kt][b0 + 4] * ej, s[kt][b0 + 5] * ej);
      uint32 D = pkh(s[kt][b0 + 6] * ej, s[kt][b0 + 7] * ej);
      asm("v_permlane32_swap_b32 %0, %1" : "+v"(A), "+v"(C));
      asm("v_permlane32_swap_b32 %0, %1" : "+v"(B), "+v"(D));
      union { uint32 w4[4]; f16x8 v; } pa;
      pa.w4[0] = A; pa.w4[1] = B; pa.w4[2] = C; pa.w4[3] = D;
      const int boff = (ks * 32 + hi * 16) ^ rsw;
#pragma unroll
      for (int dt = 0; dt < 4; ++dt) {
        f16x8 vf = *(const f16x8*)((const char*)Vs + (dt * 32 + li) * 256 + boff);
        u[dt] = __builtin_amdgcn_mfma_f32_32x32x16_f16(pa.v, vf, u[dt], 0, 0, 0);
      }
    }
    __builtin_amdgcn_s_setprio(0);

    __syncthreads();                      // all reads of Ks/Vs done
    if (kb < qt) {                        // restage same buffers
      stage_tile(KB + (size_t)(kb + 1) * 32768, 256, (char*)Ks, w, lg, ll);
      stage_tile(VB + (size_t)(kb + 1) * 256, 4096, (char*)Vs, w, lg, ll);
    }
    __syncthreads();                      // drain staging (vmcnt(0) implicit)
  }

  // ---- epilogue: O = U / l ----
  bc[w][li] = lsum;
  float rl[16];
#pragma unroll
  for (int r = 0; r < 16; ++r)
    rl[r] = 1.0f / bc[w][(r & 3) + 8 * (r >> 2) + 4 * hi];
#pragma unroll
  for (int r = 0; r < 16; ++r) {
    float* rowp =
        OB + (size_t)(qt * 128 + w * 32 + (r & 3) + 8 * (r >> 2) + 4 * hi) * DK + li;
#pragma unroll
    for (int dt = 0; dt < 4; ++dt) rowp[dt * 32] = u[dt][r] * rl[r];
  }
}

extern "C" void kernel_launch(void* const* d_in, const int* in_sizes, int n_in,
                              void* d_out, int out_size, void* d_ws, size_t ws_size,
                              hipStream_t stream) {
  const float* Q = (const float*)d_in[0];
  const float* K = (const float*)d_in[1];
  const float* V = (const float*)d_in[2];
  float* O = (float*)d_out;
  (void)in_sizes; (void)n_in; (void)out_size; (void)ws_size;

  f16* Kh = (f16*)d_ws;                          // 16 MB
  f16* Vt = (f16*)((char*)d_ws + 16777216);      // 16 MB (needs ws >= 32MB)

  prep_kv<<<dim3(16, 32), 256, 0, stream>>>(K, V, Kh, Vt);
  fa_fwd_f16<<<512, 256, 0, stream>>>(Q, Kh, Vt, O);
}